// Round 1
// baseline (262.784 us; speedup 1.0000x reference)
//
#include <hip/hip_runtime.h>

// Cotan Laplacian: V=8192 vertices, F=16384 faces, dense fp32 output (V,V).
// Output is 256 MiB -> write-BW bound; zero-fill dominates (~43 us roofline).

#define NV 8192
#define NF 16384

__global__ __launch_bounds__(256) void cotan_scatter(
    const float* __restrict__ fs,     // (V,3)
    const int*   __restrict__ faces,  // (F,3)
    float*       __restrict__ L)      // (V,V), pre-zeroed
{
    int f = blockIdx.x * blockDim.x + threadIdx.x;
    if (f >= NF) return;

    int a = faces[3 * f + 0];
    int b = faces[3 * f + 1];
    int c = faces[3 * f + 2];

    float Ax = fs[3 * a + 0], Ay = fs[3 * a + 1], Az = fs[3 * a + 2];
    float Bx = fs[3 * b + 0], By = fs[3 * b + 1], Bz = fs[3 * b + 2];
    float Cx = fs[3 * c + 0], Cy = fs[3 * c + 1], Cz = fs[3 * c + 2];

    // corner: angle at opposite vertex between u and v; scatter to edge (tail,tip)
    auto corner = [&](float ux, float uy, float uz,
                      float vx, float vy, float vz,
                      int tail, int tip) {
        float d  = ux * vx + uy * vy + uz * vz;           // |u||v| cos(a)
        float cx = uy * vz - uz * vy;
        float cy = uz * vx - ux * vz;
        float cz = ux * vy - uy * vx;
        float s  = sqrtf(cx * cx + cy * cy + cz * cz);    // |u||v| sin(a)
        float w  = 0.5f * d / s;                          // 0.5 * cot(a)

        atomicAdd(&L[(size_t)tail * NV + tip],  w);
        atomicAdd(&L[(size_t)tip  * NV + tail], w);
        atomicAdd(&L[(size_t)tail * NV + tail], -w);
        atomicAdd(&L[(size_t)tip  * NV + tip],  -w);
    };

    // slot 0: angle at B, edge (a,c)
    corner(Bx - Ax, By - Ay, Bz - Az,  Bx - Cx, By - Cy, Bz - Cz,  a, c);
    // slot 1: angle at C, edge (b,a)
    corner(Cx - Bx, Cy - By, Cz - Bz,  Cx - Ax, Cy - Ay, Cz - Az,  b, a);
    // slot 2: angle at A, edge (c,b)
    corner(Ax - Cx, Ay - Cy, Az - Cz,  Ax - Bx, Ay - By, Az - Bz,  c, b);
}

extern "C" void kernel_launch(void* const* d_in, const int* in_sizes, int n_in,
                              void* d_out, int out_size, void* d_ws, size_t ws_size,
                              hipStream_t stream) {
    const float* fs    = (const float*)d_in[0];   // (V,3) fp32
    const int*   faces = (const int*)d_in[1];     // (F,3) int32
    float*       L     = (float*)d_out;           // (V,V) fp32

    // Harness re-poisons d_out to 0xAA before every launch -> must zero it here.
    hipMemsetAsync(L, 0, (size_t)NV * NV * sizeof(float), stream);

    cotan_scatter<<<(NF + 255) / 256, 256, 0, stream>>>(fs, faces, L);
}